// Round 6
// baseline (216.987 us; speedup 1.0000x reference)
//
#include <hip/hip_runtime.h>
#include <math.h>

#ifndef M_PI
#define M_PI 3.14159265358979323846
#endif

// Problem constants (setup_inputs: audio (32,2,441000) f32, scalar int params)
#define T_LEN      441000
#define L          16                          // samples per lane
#define TILE       (64 * L)                    // 1024 samples per wave-tile
#define WARM       256                         // warm samples, tile 0 only (16 lanes)
#define WARM_LN    (WARM / L)                  // 16 warm lanes in tile 0
#define CHAIN_OUT  (2 * TILE - WARM)           // 1792 stored samples per 2-tile chain
#define WPC        ((T_LEN + CHAIN_OUT - 1) / CHAIN_OUT)   // 247 chains per channel
#define BLOCK      256                         // 4 independent waves; no barriers, no LDS
#define BLK_X      ((WPC + 3) / 4)             // 62 blocks in x per channel

// d_ws layout (floats):
//   [0..4]            b0,b1,b2,a1,a2
//   [5+4j .. 8+4j]    M^(16*2^j) row-major, j=0..5          (scan levels; [5..8] = M^16)
//   [29+2k, 30+2k]    first row of M^(k+1), k=0..15         (output correction)

__device__ __forceinline__ double log_scale(double v, double mn, double mx) {
    v = fmin(fmax(v, mn), mx);
    double lmin = log(fmax(mn, 1e-6));
    double lmax = log(mx);
    double nrm = (log(fmax(v, 1e-6)) - lmin) / (lmax - lmin);
    return nrm * (mx - mn) + mn;
}

__global__ void eq_setup_kernel(const int* __restrict__ f_in,
                                const int* __restrict__ g_in,
                                const int* __restrict__ q_in,
                                float* __restrict__ ws) {
    // Single thread; all double math to match the numpy coefficient path.
    double f = log_scale((double)f_in[0], 20.0, 20000.0);
    double g = fmin(fmax((double)g_in[0], -30.0), 30.0);
    double Q = log_scale((double)q_in[0], 0.1, 30.0);
    double w0 = 2.0 * M_PI * f / 44100.0;
    double A  = pow(10.0, g / 40.0);
    double al = sin(w0) / (2.0 * Q);
    double ca = cos(w0);
    double b0 = 1.0 + al * A;
    double b1 = -2.0 * ca;
    double b2 = 1.0 - al * A;
    double a0 = 1.0 + al / A;
    double B0 = b0 / a0, B1 = b1 / a0, B2 = b2 / a0;
    double A1 = b1 / a0, A2 = (1.0 - al / A) / a0;
    ws[0] = (float)B0; ws[1] = (float)B1; ws[2] = (float)B2;
    ws[3] = (float)A1; ws[4] = (float)A2;

    // M = [[-a1, -a2], [1, 0]] acting on (y_n, y_{n-1}).
    const double m11 = -A1, m12 = -A2;

    // Scan matrices: M^16 .. M^512 by repeated squaring (double).
    double p11 = m11, p12 = m12, p21 = 1.0, p22 = 0.0;
    for (int i = 0; i < 4; ++i) {            // -> M^16
        double s11 = p11 * p11 + p12 * p21;
        double s12 = p11 * p12 + p12 * p22;
        double s21 = p21 * p11 + p22 * p21;
        double s22 = p21 * p12 + p22 * p22;
        p11 = s11; p12 = s12; p21 = s21; p22 = s22;
    }
    for (int j = 0; j < 6; ++j) {            // store M^(16*2^j), j=0..5
        ws[5 + 4 * j + 0] = (float)p11;
        ws[5 + 4 * j + 1] = (float)p12;
        ws[5 + 4 * j + 2] = (float)p21;
        ws[5 + 4 * j + 3] = (float)p22;
        double s11 = p11 * p11 + p12 * p21;
        double s12 = p11 * p12 + p12 * p22;
        double s21 = p21 * p11 + p22 * p21;
        double s22 = p21 * p12 + p22 * p22;
        p11 = s11; p12 = s12; p21 = s21; p22 = s22;
    }

    // Correction rows: first row of M^(k+1), k=0..15.
    // y_exact[k] = y_local[k] + (M^(k+1))_11 * s0 + (M^(k+1))_12 * s1,
    // where s = (y_-1, y_-2) is the lane's incoming state.
    double q11 = m11, q12 = m12, q21 = 1.0, q22 = 0.0;   // = M^1
    for (int k = 0; k < L; ++k) {
        ws[29 + 2 * k] = (float)q11;
        ws[30 + 2 * k] = (float)q12;
        const double n11 = m11 * q11 + m12 * q21;
        const double n12 = m11 * q12 + m12 * q22;
        q21 = q11; q22 = q12;
        q11 = n11; q12 = n12;
    }
}

__device__ __forceinline__ void load_tile(const float* __restrict__ xc, int base,
                                          float4& vm, float4& v0, float4& v1,
                                          float4& v2, float4& v3) {
    if (base >= 4 && base + L <= T_LEN) {
        vm = *reinterpret_cast<const float4*>(xc + base - 4);
        v0 = *reinterpret_cast<const float4*>(xc + base + 0);
        v1 = *reinterpret_cast<const float4*>(xc + base + 4);
        v2 = *reinterpret_cast<const float4*>(xc + base + 8);
        v3 = *reinterpret_cast<const float4*>(xc + base + 12);
    } else {
        float e[20];
#pragma unroll
        for (int k = 0; k < 20; ++k) {
            const int idx = base - 4 + k;
            e[k] = (idx >= 0 && idx < T_LEN) ? xc[idx] : 0.f;
        }
        vm = make_float4(e[0],  e[1],  e[2],  e[3]);
        v0 = make_float4(e[4],  e[5],  e[6],  e[7]);
        v1 = make_float4(e[8],  e[9],  e[10], e[11]);
        v2 = make_float4(e[12], e[13], e[14], e[15]);
        v3 = make_float4(e[16], e[17], e[18], e[19]);
    }
}

// One tile: fused local pass -> scan (with exact incoming chain-state fold at lane 0)
// -> exclusive shift -> linear output correction + stores. Updates g to the tile's
// outgoing state (exact). All data arrives in registers (pre-loaded by caller).
__device__ __forceinline__ void tile_pass(const float* __restrict__ ws, int lane,
        float4 vm, float4 v0, float4 v1, float4 v2, float4 v3,
        bool first, float& g0, float& g1,
        float* __restrict__ yc, int base, bool gate) {
    const float b0 = ws[0], b1 = ws[1], b2 = ws[2], a1 = ws[3], a2 = ws[4];

    float xv[L];
    xv[0]=v0.x;  xv[1]=v0.y;  xv[2]=v0.z;  xv[3]=v0.w;
    xv[4]=v1.x;  xv[5]=v1.y;  xv[6]=v1.z;  xv[7]=v1.w;
    xv[8]=v2.x;  xv[9]=v2.y;  xv[10]=v2.z; xv[11]=v2.w;
    xv[12]=v3.x; xv[13]=v3.y; xv[14]=v3.z; xv[15]=v3.w;
    const float xm2 = vm.z, xm1 = vm.w;

    // Fused local pass: FIR + zero-state IIR; record local outputs yl[k].
    float yl[L];
    float c0 = 0.f, c1 = 0.f;                  // (y_n, y_{n-1}) zero-state
    {
        float xk1 = xm1, xk2 = xm2;
#pragma unroll
        for (int k = 0; k < L; ++k) {
            const float xk = xv[k];
            const float t  = fmaf(b0, xk, fmaf(b1, xk1, b2 * xk2));
            const float yn = fmaf(-a1, c0, fmaf(-a2, c1, t));
            c1 = c0; c0 = yn;
            xk2 = xk1; xk1 = xk;
            yl[k] = yn;
        }
    }

    // Fold exact incoming chain state g into lane 0 (outgoing lane0 = M^16*g + local).
    if (!first && lane == 0) {
        const float n0 = fmaf(ws[5], g0, fmaf(ws[6], g1, c0));
        const float n1 = fmaf(ws[7], g0, fmaf(ws[8], g1, c1));
        c0 = n0; c1 = n1;
    }

    // Inclusive affine wave scan; level j composes with A = M^(16*2^j).
#pragma unroll
    for (int j = 0; j < 6; ++j) {
        const float m11 = ws[5 + 4 * j + 0], m12 = ws[5 + 4 * j + 1];
        const float m21 = ws[5 + 4 * j + 2], m22 = ws[5 + 4 * j + 3];
        const float d0 = __shfl_up(c0, 1u << j);
        const float d1 = __shfl_up(c1, 1u << j);
        if (lane >= (1 << j)) {
            c0 = fmaf(m11, d0, fmaf(m12, d1, c0));
            c1 = fmaf(m21, d0, fmaf(m22, d1, c1));
        }
    }

    // Outgoing chain state (exact), exclusive shift for per-lane incoming state.
    const float ng0 = __shfl(c0, 63), ng1 = __shfl(c1, 63);
    float s0 = __shfl_up(c0, 1);
    float s1 = __shfl_up(c1, 1);
    if (lane == 0) { s0 = first ? 0.f : g0; s1 = first ? 0.f : g1; }
    g0 = ng0; g1 = ng1;

    // Linear output correction (2 FMAs/sample, fully parallel) + stores.
    if (gate && base < T_LEN) {
        if (base + L <= T_LEN) {
#pragma unroll
            for (int q = 0; q < L / 4; ++q) {
                float o[4];
#pragma unroll
                for (int r = 0; r < 4; ++r) {
                    const int k = 4 * q + r;
                    o[r] = fmaf(ws[29 + 2 * k], s0, fmaf(ws[30 + 2 * k], s1, yl[k]));
                }
                *reinterpret_cast<float4*>(yc + base + 4 * q) =
                    make_float4(o[0], o[1], o[2], o[3]);
            }
        } else {
#pragma unroll
            for (int k = 0; k < L; ++k)
                if (base + k < T_LEN)
                    yc[base + k] = fmaf(ws[29 + 2 * k], s0, fmaf(ws[30 + 2 * k], s1, yl[k]));
        }
    }
}

// Wave-independent 2-tile pipelined chains, plain HIP. BOTH tiles' loads are issued
// in the prologue (10 float4 in flight per lane); tile-0 compute runs under tile-1's
// load latency, tile-0 stores overlap tile-1 compute. Generous launch_bounds (128
// VGPR cap) so the compiler has no pressure to sink/remat the tile-1 prefetch.
__global__ __launch_bounds__(BLOCK, 4) void eq_main_kernel(
        const float* __restrict__ x,
        const float* __restrict__ ws,
        float* __restrict__ y) {
    const int tid   = threadIdx.x;
    const int lane  = tid & 63;
    const int wv    = tid >> 6;
    const int chain = blockIdx.x * (BLOCK / 64) + wv;   // 0..246 active
    if (chain >= WPC) return;                            // wave-uniform exit
    const int ch = blockIdx.y;

    const float* __restrict__ xc = x + (size_t)ch * T_LEN;
    float*       __restrict__ yc = y + (size_t)ch * T_LEN;

    const int base0 = chain * CHAIN_OUT - WARM + lane * L;   // mult of 16, can be <0
    const int base1 = base0 + TILE;

    // ---- Prologue: issue ALL 10 loads (both tiles) before any compute.
    float4 Am, A0, A1, A2, A3, Bm, B0, B1, B2, B3;
    load_tile(xc, base0, Am, A0, A1, A2, A3);
    load_tile(xc, base1, Bm, B0, B1, B2, B3);

    float g0 = 0.f, g1 = 0.f;
    // Tile 0: zero initial state; first WARM_LN lanes are warm-up (not stored).
    tile_pass(ws, lane, Am, A0, A1, A2, A3, true,  g0, g1, yc, base0, lane >= WARM_LN);
    // Tile 1: exact carried state; all lanes stored.
    tile_pass(ws, lane, Bm, B0, B1, B2, B3, false, g0, g1, yc, base1, true);
}

extern "C" void kernel_launch(void* const* d_in, const int* in_sizes, int n_in,
                              void* d_out, int out_size, void* d_ws, size_t ws_size,
                              hipStream_t stream) {
    const float* x = (const float*)d_in[0];
    const int*   f = (const int*)d_in[1];
    const int*   g = (const int*)d_in[2];
    const int*   q = (const int*)d_in[3];
    float*       y  = (float*)d_out;
    float*       ws = (float*)d_ws;

    eq_setup_kernel<<<1, 1, 0, stream>>>(f, g, q, ws);

    const int nch = in_sizes[0] / T_LEN;   // 64 for this problem
    dim3 grid(BLK_X, nch);
    eq_main_kernel<<<grid, dim3(BLOCK), 0, stream>>>(x, ws, y);
}

// Round 8
// 215.809 us; speedup vs baseline: 1.0055x; 1.0055x over previous
//
#include <hip/hip_runtime.h>
#include <math.h>

#ifndef M_PI
#define M_PI 3.14159265358979323846
#endif

// Problem constants (setup_inputs: audio (32,2,441000) f32, scalar int params)
#define T_LEN      441000
#define L          16                          // samples per lane
#define TILE       (64 * L)                    // 1024 samples per wave-tile
#define WARM       256                         // warm samples, tile 0 only (16 lanes)
#define WARM_LN    (WARM / L)                  // 16 warm lanes in tile 0
#define CHAIN_OUT  (2 * TILE - WARM)           // 1792 stored samples per 2-tile chain
#define WPC        ((T_LEN + CHAIN_OUT - 1) / CHAIN_OUT)   // 247 chains per channel
#define BLOCK      256                         // 4 independent waves; no barriers, no LDS
#define BLK_X      ((WPC + 3) / 4)             // 62 blocks in x per channel

// d_ws layout (floats):
//   [0..4]            b0,b1,b2,a1,a2
//   [5+4j .. 8+4j]    M^(16*2^j) row-major, j=0..5          (scan levels; [5..8] = M^16)
//   [29+2k, 30+2k]    first row of M^(k+1), k=0..15         (output correction)

// Scalar-component keep-live pin (gfx950 clang rejects 128-bit "v" asm operands).
#define PIN4(v) asm volatile("" :: "v"((v).x), "v"((v).y), "v"((v).z), "v"((v).w))

__device__ __forceinline__ double log_scale(double v, double mn, double mx) {
    v = fmin(fmax(v, mn), mx);
    double lmin = log(fmax(mn, 1e-6));
    double lmax = log(mx);
    double nrm = (log(fmax(v, 1e-6)) - lmin) / (lmax - lmin);
    return nrm * (mx - mn) + mn;
}

__global__ void eq_setup_kernel(const int* __restrict__ f_in,
                                const int* __restrict__ g_in,
                                const int* __restrict__ q_in,
                                float* __restrict__ ws) {
    // Single thread; all double math to match the numpy coefficient path.
    double f = log_scale((double)f_in[0], 20.0, 20000.0);
    double g = fmin(fmax((double)g_in[0], -30.0), 30.0);
    double Q = log_scale((double)q_in[0], 0.1, 30.0);
    double w0 = 2.0 * M_PI * f / 44100.0;
    double A  = pow(10.0, g / 40.0);
    double al = sin(w0) / (2.0 * Q);
    double ca = cos(w0);
    double b0 = 1.0 + al * A;
    double b1 = -2.0 * ca;
    double b2 = 1.0 - al * A;
    double a0 = 1.0 + al / A;
    double B0 = b0 / a0, B1 = b1 / a0, B2 = b2 / a0;
    double A1 = b1 / a0, A2 = (1.0 - al / A) / a0;
    ws[0] = (float)B0; ws[1] = (float)B1; ws[2] = (float)B2;
    ws[3] = (float)A1; ws[4] = (float)A2;

    // M = [[-a1, -a2], [1, 0]] acting on (y_n, y_{n-1}).
    const double m11 = -A1, m12 = -A2;

    // Scan matrices: M^16 .. M^512 by repeated squaring (double).
    double p11 = m11, p12 = m12, p21 = 1.0, p22 = 0.0;
    for (int i = 0; i < 4; ++i) {            // -> M^16
        double s11 = p11 * p11 + p12 * p21;
        double s12 = p11 * p12 + p12 * p22;
        double s21 = p21 * p11 + p22 * p21;
        double s22 = p21 * p12 + p22 * p22;
        p11 = s11; p12 = s12; p21 = s21; p22 = s22;
    }
    for (int j = 0; j < 6; ++j) {            // store M^(16*2^j), j=0..5
        ws[5 + 4 * j + 0] = (float)p11;
        ws[5 + 4 * j + 1] = (float)p12;
        ws[5 + 4 * j + 2] = (float)p21;
        ws[5 + 4 * j + 3] = (float)p22;
        double s11 = p11 * p11 + p12 * p21;
        double s12 = p11 * p12 + p12 * p22;
        double s21 = p21 * p11 + p22 * p21;
        double s22 = p21 * p12 + p22 * p22;
        p11 = s11; p12 = s12; p21 = s21; p22 = s22;
    }

    // Correction rows: first row of M^(k+1), k=0..15.
    // y_exact[k] = y_local[k] + (M^(k+1))_11 * s0 + (M^(k+1))_12 * s1,
    // where s = (y_-1, y_-2) is the lane's incoming state.
    double q11 = m11, q12 = m12, q21 = 1.0, q22 = 0.0;   // = M^1
    for (int k = 0; k < L; ++k) {
        ws[29 + 2 * k] = (float)q11;
        ws[30 + 2 * k] = (float)q12;
        const double n11 = m11 * q11 + m12 * q21;
        const double n12 = m11 * q12 + m12 * q22;
        q21 = q11; q22 = q12;
        q11 = n11; q12 = n12;
    }
}

__device__ __forceinline__ void load_tile(const float* __restrict__ xc, int base,
                                          float4& vm, float4& v0, float4& v1,
                                          float4& v2, float4& v3) {
    if (base >= 4 && base + L <= T_LEN) {
        vm = *reinterpret_cast<const float4*>(xc + base - 4);
        v0 = *reinterpret_cast<const float4*>(xc + base + 0);
        v1 = *reinterpret_cast<const float4*>(xc + base + 4);
        v2 = *reinterpret_cast<const float4*>(xc + base + 8);
        v3 = *reinterpret_cast<const float4*>(xc + base + 12);
    } else {
        float e[20];
#pragma unroll
        for (int k = 0; k < 20; ++k) {
            const int idx = base - 4 + k;
            e[k] = (idx >= 0 && idx < T_LEN) ? xc[idx] : 0.f;
        }
        vm = make_float4(e[0],  e[1],  e[2],  e[3]);
        v0 = make_float4(e[4],  e[5],  e[6],  e[7]);
        v1 = make_float4(e[8],  e[9],  e[10], e[11]);
        v2 = make_float4(e[12], e[13], e[14], e[15]);
        v3 = make_float4(e[16], e[17], e[18], e[19]);
    }
}

// One tile: fused local pass -> scan (with exact incoming chain-state fold at lane 0)
// -> exclusive shift -> linear output correction + stores. Updates g to the tile's
// outgoing state (exact). All data arrives in registers (pre-loaded by caller).
__device__ __forceinline__ void tile_pass(const float* __restrict__ ws, int lane,
        float4 vm, float4 v0, float4 v1, float4 v2, float4 v3,
        bool first, float& g0, float& g1,
        float* __restrict__ yc, int base, bool gate) {
    const float b0 = ws[0], b1 = ws[1], b2 = ws[2], a1 = ws[3], a2 = ws[4];

    float xv[L];
    xv[0]=v0.x;  xv[1]=v0.y;  xv[2]=v0.z;  xv[3]=v0.w;
    xv[4]=v1.x;  xv[5]=v1.y;  xv[6]=v1.z;  xv[7]=v1.w;
    xv[8]=v2.x;  xv[9]=v2.y;  xv[10]=v2.z; xv[11]=v2.w;
    xv[12]=v3.x; xv[13]=v3.y; xv[14]=v3.z; xv[15]=v3.w;
    const float xm2 = vm.z, xm1 = vm.w;

    // Fused local pass: FIR + zero-state IIR; record local outputs yl[k].
    float yl[L];
    float c0 = 0.f, c1 = 0.f;                  // (y_n, y_{n-1}) zero-state
    {
        float xk1 = xm1, xk2 = xm2;
#pragma unroll
        for (int k = 0; k < L; ++k) {
            const float xk = xv[k];
            const float t  = fmaf(b0, xk, fmaf(b1, xk1, b2 * xk2));
            const float yn = fmaf(-a1, c0, fmaf(-a2, c1, t));
            c1 = c0; c0 = yn;
            xk2 = xk1; xk1 = xk;
            yl[k] = yn;
        }
    }

    // Fold exact incoming chain state g into lane 0 (outgoing lane0 = M^16*g + local).
    if (!first && lane == 0) {
        const float n0 = fmaf(ws[5], g0, fmaf(ws[6], g1, c0));
        const float n1 = fmaf(ws[7], g0, fmaf(ws[8], g1, c1));
        c0 = n0; c1 = n1;
    }

    // Inclusive affine wave scan; level j composes with A = M^(16*2^j).
#pragma unroll
    for (int j = 0; j < 6; ++j) {
        const float m11 = ws[5 + 4 * j + 0], m12 = ws[5 + 4 * j + 1];
        const float m21 = ws[5 + 4 * j + 2], m22 = ws[5 + 4 * j + 3];
        const float d0 = __shfl_up(c0, 1u << j);
        const float d1 = __shfl_up(c1, 1u << j);
        if (lane >= (1 << j)) {
            c0 = fmaf(m11, d0, fmaf(m12, d1, c0));
            c1 = fmaf(m21, d0, fmaf(m22, d1, c1));
        }
    }

    // Outgoing chain state (exact), exclusive shift for per-lane incoming state.
    const float ng0 = __shfl(c0, 63), ng1 = __shfl(c1, 63);
    float s0 = __shfl_up(c0, 1);
    float s1 = __shfl_up(c1, 1);
    if (lane == 0) { s0 = first ? 0.f : g0; s1 = first ? 0.f : g1; }
    g0 = ng0; g1 = ng1;

    // Linear output correction (2 FMAs/sample, fully parallel) + stores.
    if (gate && base < T_LEN) {
        if (base + L <= T_LEN) {
#pragma unroll
            for (int q = 0; q < L / 4; ++q) {
                float o[4];
#pragma unroll
                for (int r = 0; r < 4; ++r) {
                    const int k = 4 * q + r;
                    o[r] = fmaf(ws[29 + 2 * k], s0, fmaf(ws[30 + 2 * k], s1, yl[k]));
                }
                *reinterpret_cast<float4*>(yc + base + 4 * q) =
                    make_float4(o[0], o[1], o[2], o[3]);
            }
        } else {
#pragma unroll
            for (int k = 0; k < L; ++k)
                if (base + k < T_LEN)
                    yc[base + k] = fmaf(ws[29 + 2 * k], s0, fmaf(ws[30 + 2 * k], s1, yl[k]));
        }
    }
}

// Wave-independent 2-tile chains. BOTH tiles' loads are issued AND PINNED in the
// prologue: the scalar-component asm pins below USE all 40 loaded floats, so the
// backend must materialize every load before this point (10 concurrent loads per
// lane, latencies overlap), and sched_barrier(0) stops the machine scheduler from
// sinking any of them into the compute (r6 evidence: without the pin,
// VGPR_Count=28 proved tile-1's loads were sunk below tile-0's compute,
// serializing the two latency exposures).
__global__ __launch_bounds__(BLOCK, 4) void eq_main_kernel(
        const float* __restrict__ x,
        const float* __restrict__ ws,
        float* __restrict__ y) {
    const int tid   = threadIdx.x;
    const int lane  = tid & 63;
    const int wv    = tid >> 6;
    const int chain = blockIdx.x * (BLOCK / 64) + wv;   // 0..246 active
    if (chain >= WPC) return;                            // wave-uniform exit
    const int ch = blockIdx.y;

    const float* __restrict__ xc = x + (size_t)ch * T_LEN;
    float*       __restrict__ yc = y + (size_t)ch * T_LEN;

    const int base0 = chain * CHAIN_OUT - WARM + lane * L;   // mult of 16, can be <0
    const int base1 = base0 + TILE;

    // ---- Prologue: issue ALL 10 loads (both tiles) before any compute.
    float4 Am, A0, A1, A2, A3, Bm, B0, B1, B2, B3;
    load_tile(xc, base0, Am, A0, A1, A2, A3);
    load_tile(xc, base1, Bm, B0, B1, B2, B3);

    // Keep-live pin: all 10 loads complete HERE, concurrently.
    PIN4(Am); PIN4(A0); PIN4(A1); PIN4(A2); PIN4(A3);
    PIN4(Bm); PIN4(B0); PIN4(B1); PIN4(B2); PIN4(B3);
    __builtin_amdgcn_sched_barrier(0);

    float g0 = 0.f, g1 = 0.f;
    // Tile 0: zero initial state; first WARM_LN lanes are warm-up (not stored).
    tile_pass(ws, lane, Am, A0, A1, A2, A3, true,  g0, g1, yc, base0, lane >= WARM_LN);
    // Tile 1: exact carried state; all lanes stored.
    tile_pass(ws, lane, Bm, B0, B1, B2, B3, false, g0, g1, yc, base1, true);
}

extern "C" void kernel_launch(void* const* d_in, const int* in_sizes, int n_in,
                              void* d_out, int out_size, void* d_ws, size_t ws_size,
                              hipStream_t stream) {
    const float* x = (const float*)d_in[0];
    const int*   f = (const int*)d_in[1];
    const int*   g = (const int*)d_in[2];
    const int*   q = (const int*)d_in[3];
    float*       y  = (float*)d_out;
    float*       ws = (float*)d_ws;

    eq_setup_kernel<<<1, 1, 0, stream>>>(f, g, q, ws);

    const int nch = in_sizes[0] / T_LEN;   // 64 for this problem
    dim3 grid(BLK_X, nch);
    eq_main_kernel<<<grid, dim3(BLOCK), 0, stream>>>(x, ws, y);
}